// Round 2
// 859.171 us; speedup vs baseline: 1.1219x; 1.1219x over previous
//
#include <hip/hip_runtime.h>
#include <hip/hip_bf16.h>

// ImplicitRNNCell, R9: 3-round structure (R8) with the atomicAdd path REMOVED.
// R8 post-mortem: device-scope atomicAdd executes at the cross-XCD coherence
// point (memory-side), while the relaxed agent zero-store + ld64 readers use
// the local L2 (CDNA L1 is write-through; sc0 loads read L2). Two coherence
// points for the same lines -> readers saw stale L2 copies / the dirty zero
// line wrote back over the sums. Fix: partial-h exchange is now PURE ld/st
// via the R5/R7-proven mechanism (relaxed agent st64 -> __syncthreads vmcnt
// drain -> flag -> poll -> relaxed agent ld64), same as Xex. Consumers sum
// the 8 f32 partials when staging u (~128KB/WG/t of L2 reads, ~1us).
//   - FENCELESS same-XCD mode kept (runtime s_getreg(XCC_ID) check; fenced
//     R7-identical fallback on any anomaly). Fence cost ~1.9us each, 3/t.
//   - Rounds/t: 3 (X1, X2, H). X3 stays local (f32 -> hi/lo LDS), h partial
//     = C[:, own64] @ X3_local + D@u(own 32 rows), summed consumer-side.
//   - Hpart single-buffered: end-of-t stores are ordered after all start-of-t
//     reads via the X1 flag round (readers' loads drain before X1 flag post).
//   - h is f32 end-to-end -> accuracy >= R7 (absmax 0.25).

typedef __bf16 bf16x8 __attribute__((ext_vector_type(8)));
typedef __bf16 bf16x4 __attribute__((ext_vector_type(4)));
typedef float  f32x4  __attribute__((ext_vector_type(4)));
typedef unsigned int       u32;
typedef unsigned long long u64;

#define B_SZ   512
#define SEQ    64
#define IN_DIM 128
#define HID    256
#define NIMP   512
#define PDIM   384
#define NITERS_EFF 3
#define BC     16
#define GW     8
#define NEV    4    // idx0=X1, idx1=X2, idx2=H, idx3=init/XCD-id
#define UPAD   392
#define XPAD   520
#define X3PAD  72

__device__ __forceinline__ unsigned short bfb(float f) {
    __bf16 b = (__bf16)f;
    return __builtin_bit_cast(unsigned short, b);
}
__device__ __forceinline__ void st64(u64* p, u64 v) {
    __hip_atomic_store(p, v, __ATOMIC_RELAXED, __HIP_MEMORY_SCOPE_AGENT);
}
__device__ __forceinline__ u64 ld64(const u64* p) {
    return __hip_atomic_load(p, __ATOMIC_RELAXED, __HIP_MEMORY_SCOPE_AGENT);
}
__device__ __forceinline__ u32 ld32sys(const u32* p) {
    return __hip_atomic_load(p, __ATOMIC_RELAXED, __HIP_MEMORY_SCOPE_SYSTEM);
}
__device__ __forceinline__ u64 packf2(float a, float b) {
    return ((u64)__builtin_bit_cast(u32, b) << 32) | __builtin_bit_cast(u32, a);
}

__global__ void convert_plain(const float* __restrict__ src,
                              __bf16* __restrict__ dst, int n4) {
    int i = blockIdx.x * blockDim.x + threadIdx.x;
    if (i >= n4) return;
    float4 v = reinterpret_cast<const float4*>(src)[i];
    bf16x4 o;
    o[0] = (__bf16)v.x; o[1] = (__bf16)v.y; o[2] = (__bf16)v.z; o[3] = (__bf16)v.w;
    reinterpret_cast<bf16x4*>(dst)[i] = o;
}

__global__ void convert_split(const float* __restrict__ src,
                              __bf16* __restrict__ hi, __bf16* __restrict__ lo,
                              int n4) {
    int i = blockIdx.x * blockDim.x + threadIdx.x;
    if (i >= n4) return;
    float4 v = reinterpret_cast<const float4*>(src)[i];
    float f[4] = {v.x, v.y, v.z, v.w};
    bf16x4 h, l;
#pragma unroll
    for (int e = 0; e < 4; ++e) {
        __bf16 hh = (__bf16)f[e];
        h[e] = hh;
        l[e] = (__bf16)(f[e] - (float)hh);
    }
    reinterpret_cast<bf16x4*>(hi)[i] = h;
    reinterpret_cast<bf16x4*>(lo)[i] = l;
}

__global__ void zero_u32(u32* __restrict__ p, int n) {
    int i = blockIdx.x * blockDim.x + threadIdx.x;
    if (i < n) p[i] = 0;
}

// wave 0 only: poll 8 per-WG flags (64B apart) RELAXED until all == tok.
// fence=true: R7-identical acquire (safe cross-XCD). fence=false (runtime-
// verified same-XCD): compiler barrier only — producer stores drained to the
// shared local L2 (vmcnt(0) at producer's __syncthreads) before its flag; our
// sc0 loads read that same L2.
__device__ __forceinline__ void group_wait(u32* f, u32 tok, int lane, bool fence) {
    while (true) {
        u32 v = (lane < GW)
            ? __hip_atomic_load(f + lane * 16, __ATOMIC_RELAXED, __HIP_MEMORY_SCOPE_AGENT)
            : tok;
        if (__ballot(v == tok) == ~0ull) break;
        __builtin_amdgcn_s_sleep(1);
    }
    if (fence) __builtin_amdgcn_fence(__ATOMIC_ACQUIRE, "agent");
    else       asm volatile("" ::: "memory");
}

__global__ __launch_bounds__(512, 2)
void rnn_kernel(const float* __restrict__ x,
                const __bf16* __restrict__ Abf,
                const __bf16* __restrict__ Bhi, const __bf16* __restrict__ Blo,
                const __bf16* __restrict__ Chi, const __bf16* __restrict__ Clo,
                const __bf16* __restrict__ Dhi, const __bf16* __restrict__ Dlo,
                float* __restrict__ out,
                u32* __restrict__ flags,   // [32][NEV][8*16]
                u32* __restrict__ Xex,     // [2][32][16][256] packed row-pairs (hi)
                float* __restrict__ Hpart) {// [32][8][16][256] f32 partial h
    __shared__ __bf16 Xhi[BC][XPAD];
    __shared__ __bf16 Xlo3[BC][X3PAD];   // X3 lo, local staging only (64 k)
    __shared__ __bf16 u_hi[BC][UPAD];
    __shared__ __bf16 u_lo[BC][UPAD];
    __shared__ f32x4  red4[10][64];      // 0..3: bu / A-it ; 4..9: D-part
    __shared__ float  dsum[32][16];      // D@u rows [32*sub,+32)
    __shared__ int    s_nofence;

    const int tid  = threadIdx.x;
    const int wave = tid >> 6;
    const int lane = tid & 63;
    const int quad = lane >> 4;
    const int l16  = lane & 15;
    const int g    = blockIdx.x & 31;   // blocks {g, g+32k}: same XCD under %8 map
    const int sub  = blockIdx.x >> 5;   // 0..7
    const int R0   = sub * 64;
    const int H0   = sub * 32;
    const int b0   = g * BC;
    const int m    = wave & 3;
    const int kh   = wave >> 2;
    const int m2   = wave & 1;
    const int kh4  = wave >> 1;

    // ---- preload weight fragments ----
    bf16x8 aF[8], bFh[6], bFl[6], cFh[2][2], cFl[2][2], dFh[3], dFl[3];
    {
        const int arow = R0 + m * 16 + l16;
#pragma unroll
        for (int s = 0; s < 8; ++s)
            aF[s] = *reinterpret_cast<const bf16x8*>(
                &Abf[arow * NIMP + (kh * 8 + s) * 32 + quad * 8]);
#pragma unroll
        for (int s = 0; s < 6; ++s) {
            const int o = arow * PDIM + (kh * 6 + s) * 32 + quad * 8;
            bFh[s] = *reinterpret_cast<const bf16x8*>(&Bhi[o]);
            bFl[s] = *reinterpret_cast<const bf16x8*>(&Blo[o]);
        }
        // partial-h: wave w owns h-rows [32w, +32), K-slice = own X rows [R0,+64)
#pragma unroll
        for (int tl = 0; tl < 2; ++tl)
#pragma unroll
        for (int s = 0; s < 2; ++s) {
            const int o = (32 * wave + tl * 16 + l16) * NIMP + R0 + s * 32 + quad * 8;
            cFh[tl][s] = *reinterpret_cast<const bf16x8*>(&Chi[o]);
            cFl[tl][s] = *reinterpret_cast<const bf16x8*>(&Clo[o]);
        }
        const int hrow = H0 + m2 * 16 + l16;
#pragma unroll
        for (int s = 0; s < 3; ++s) {
            const int o = hrow * PDIM + (kh4 * 3 + s) * 32 + quad * 8;
            dFh[s] = *reinterpret_cast<const bf16x8*>(&Dhi[o]);
            dFl[s] = *reinterpret_cast<const bf16x8*>(&Dlo[o]);
        }
    }

    u32* const fg   = flags + g * (NEV * GW * 16);
    const int xcol  = tid >> 5;   // 0..15
    const int xseg  = tid & 31;   // 0..31

    // ---- init: runtime XCD-uniformity check (decides fenceless mode) ----
    {
        u32 myid = __builtin_amdgcn_s_getreg((31u << 11) | 20u); // hwreg(XCC_ID,0,32)
        if (tid == 0)
            __hip_atomic_store(fg + 3 * (GW * 16) + sub * 16, 0x100u | (myid & 0xffu),
                               __ATOMIC_RELAXED, __HIP_MEMORY_SCOPE_SYSTEM);
        if (wave == 0) {
            u32 v = 0x100u;
            while (true) {
                v = (lane < GW) ? ld32sys(fg + 3 * (GW * 16) + lane * 16) : 0x100u;
                if (__ballot((v & 0x100u) != 0u) == ~0ull) break;
                __builtin_amdgcn_s_sleep(8);
            }
            u32 ref = __shfl((int)v, 0);
            bool same = (lane < GW) ? (v == ref) : true;
            bool allsame = (__ballot(same) == ~0ull);
            u32 nb = 0;
            if (lane == 0) {
                const u32* ns = flags + (size_t)((g + 1) & 31) * (NEV * GW * 16)
                              + 3 * (GW * 16);
                while (((nb = ld32sys(ns)) & 0x100u) == 0u)
                    __builtin_amdgcn_s_sleep(8);
            }
            nb = (u32)__shfl((int)nb, 0);
            if (lane == 0)
                s_nofence = (allsame && ((nb & 0xffu) != (ref & 0xffu))) ? 1 : 0;
        }
        __syncthreads();
    }
    const bool FEN = (s_nofence == 0);   // wave-uniform

    // consumer-side: read 8 partials, sum -> hv[8] (h rows xseg*8..+8, col xcol)
    auto read_h_sum = [&](float* hv) {
        const float* base = Hpart + (((size_t)g * 8) * 16 + xcol) * 256 + xseg * 8;
        float a0 = 0.f, a1 = 0.f, a2 = 0.f, a3 = 0.f,
              a4 = 0.f, a5 = 0.f, a6 = 0.f, a7 = 0.f;
#pragma unroll 2
        for (int s8 = 0; s8 < 8; ++s8) {
            const u64* p = reinterpret_cast<const u64*>(base + (size_t)s8 * (16 * 256));
            u64 w0 = ld64(p);
            u64 w1 = ld64(p + 1);
            u64 w2 = ld64(p + 2);
            u64 w3 = ld64(p + 3);
            a0 += __builtin_bit_cast(float, (u32)w0);
            a1 += __builtin_bit_cast(float, (u32)(w0 >> 32));
            a2 += __builtin_bit_cast(float, (u32)w1);
            a3 += __builtin_bit_cast(float, (u32)(w1 >> 32));
            a4 += __builtin_bit_cast(float, (u32)w2);
            a5 += __builtin_bit_cast(float, (u32)(w2 >> 32));
            a6 += __builtin_bit_cast(float, (u32)w3);
            a7 += __builtin_bit_cast(float, (u32)(w3 >> 32));
        }
        hv[0] = a0; hv[1] = a1; hv[2] = a2; hv[3] = a3;
        hv[4] = a4; hv[5] = a5; hv[6] = a6; hv[7] = a7;
    };

    for (int t = 0; t < SEQ; ++t) {
        const u32 tok = (u32)(t + 1);
        // ---- stage x-part of u ----
        {
            const int p4 = xseg << 2;
            float4 v = *reinterpret_cast<const float4*>(
                &x[((size_t)(b0 + xcol) * SEQ + t) * IN_DIM + p4]);
            float f[4] = {v.x, v.y, v.z, v.w};
            bf16x4 h, l;
#pragma unroll
            for (int e = 0; e < 4; ++e) {
                __bf16 hh = (__bf16)f[e];
                h[e] = hh;
                l[e] = (__bf16)(f[e] - (float)hh);
            }
            *reinterpret_cast<bf16x4*>(&u_hi[xcol][p4]) = h;
            *reinterpret_cast<bf16x4*>(&u_lo[xcol][p4]) = l;
        }
        if (t == 0) {
            bf16x8 z = {};
            *reinterpret_cast<bf16x8*>(&u_hi[xcol][IN_DIM + xseg * 8]) = z;
            *reinterpret_cast<bf16x8*>(&u_lo[xcol][IN_DIM + xseg * 8]) = z;
        } else {
            if (wave == 0) group_wait(fg + 2 * (GW * 16), (u32)t, lane, FEN);
            __syncthreads();
            float hv[8];
            read_h_sum(hv);
            bf16x8 hh, hl;
#pragma unroll
            for (int e = 0; e < 8; ++e) {
                __bf16 q = (__bf16)hv[e];
                hh[e] = q;
                hl[e] = (__bf16)(hv[e] - (float)q);
            }
            *reinterpret_cast<bf16x8*>(&u_hi[xcol][IN_DIM + xseg * 8]) = hh;
            *reinterpret_cast<bf16x8*>(&u_lo[xcol][IN_DIM + xseg * 8]) = hl;
            if ((xseg >> 2) == sub) {
                float4 o0 = {hv[0], hv[1], hv[2], hv[3]};
                float4 o1 = {hv[4], hv[5], hv[6], hv[7]};
                size_t ob = ((size_t)(b0 + xcol) * SEQ + (t - 1)) * HID + xseg * 8;
                *reinterpret_cast<float4*>(&out[ob])     = o0;
                *reinterpret_cast<float4*>(&out[ob + 4]) = o1;
            }
        }
        __syncthreads();

        // ---- bu = Bmat @ u (split, K-halved across wave pairs) ----
        f32x4 acc = {0.f, 0.f, 0.f, 0.f};
#pragma unroll
        for (int s = 0; s < 6; ++s) {
            const int k0 = (kh * 6 + s) * 32 + quad * 8;
            bf16x8 uh = *reinterpret_cast<const bf16x8*>(&u_hi[l16][k0]);
            bf16x8 ul = *reinterpret_cast<const bf16x8*>(&u_lo[l16][k0]);
            acc = __builtin_amdgcn_mfma_f32_16x16x32_bf16(bFh[s], uh, acc, 0, 0, 0);
            acc = __builtin_amdgcn_mfma_f32_16x16x32_bf16(bFh[s], ul, acc, 0, 0, 0);
            acc = __builtin_amdgcn_mfma_f32_16x16x32_bf16(bFl[s], uh, acc, 0, 0, 0);
        }
        if (kh == 1) red4[m][lane] = acc;
        __syncthreads();
        f32x4 bu_acc = acc;
        if (kh == 0) bu_acc = acc + red4[m][lane];

        // ---- broadcast own X chunk, read back all 512 rows (R5 skeleton) ----
        auto xexchange = [&](int itx, const f32x4& tot) {
            const int buf = itx & 1;
            if (kh == 0) {
                float r0f = fmaxf(tot[0], 0.f), r1f = fmaxf(tot[1], 0.f);
                float r2f = fmaxf(tot[2], 0.f), r3f = fmaxf(tot[3], 0.f);
                u32 d0 = (u32)bfb(r0f) | ((u32)bfb(r1f) << 16);
                u32 d1 = (u32)bfb(r2f) | ((u32)bfb(r3f) << 16);
                const int rp = (R0 + m * 16 + quad * 4) >> 1;
                st64(reinterpret_cast<u64*>(
                         Xex + (((size_t)buf * 32 + g) * 16 + l16) * 256 + rp),
                     ((u64)d1 << 32) | d0);
            }
            __syncthreads();  // every wave drains vmcnt(0) -> data visible
            {
                u32* f = fg + itx * (GW * 16);
                if (wave == 0) {
                    if (lane == 0)
                        __hip_atomic_store(f + sub * 16, tok, __ATOMIC_RELAXED,
                                           __HIP_MEMORY_SCOPE_AGENT);
                    group_wait(f, tok, lane, FEN);
                }
            }
            __syncthreads();
            {   // read back full X (hi)
                const u32* src = Xex + (((size_t)buf * 32 + g) * 16 + xcol) * 256;
                u64 w0 = ld64(reinterpret_cast<const u64*>(src + xseg * 4));
                u64 w1 = ld64(reinterpret_cast<const u64*>(src + xseg * 4 + 2));
                u64 w2 = ld64(reinterpret_cast<const u64*>(src + 128 + xseg * 4));
                u64 w3 = ld64(reinterpret_cast<const u64*>(src + 128 + xseg * 4 + 2));
                union { u64 q[2]; bf16x8 v; } cA, cB;
                cA.q[0] = w0; cA.q[1] = w1; cB.q[0] = w2; cB.q[1] = w3;
                *reinterpret_cast<bf16x8*>(&Xhi[xcol][xseg * 8])       = cA.v;
                *reinterpret_cast<bf16x8*>(&Xhi[xcol][256 + xseg * 8]) = cB.v;
            }
            __syncthreads();
        };

        // ---- X1 = relu(bu), round 0 ----
        xexchange(0, bu_acc);

        // ---- it=2: X2 = relu(A @ X1 + bu), round 1 ----
        {
            f32x4 p;
            if (kh == 0) p = bu_acc;
            else { p[0] = 0.f; p[1] = 0.f; p[2] = 0.f; p[3] = 0.f; }
#pragma unroll
            for (int s = 0; s < 8; ++s) {
                const int k0 = (kh * 8 + s) * 32 + quad * 8;
                bf16x8 xF = *reinterpret_cast<const bf16x8*>(&Xhi[l16][k0]);
                p = __builtin_amdgcn_mfma_f32_16x16x32_bf16(aF[s], xF, p, 0, 0, 0);
            }
            if (kh == 1) red4[m][lane] = p;
            __syncthreads();
            f32x4 tot = p;
            if (kh == 0) tot = p + red4[m][lane];
            xexchange(1, tot);
        }

        // ---- it=3: X3 = relu(A @ X2 + bu) stays LOCAL (f32 -> hi/lo LDS) ----
        {
            f32x4 p;
            if (kh == 0) p = bu_acc;
            else { p[0] = 0.f; p[1] = 0.f; p[2] = 0.f; p[3] = 0.f; }
#pragma unroll
            for (int s = 0; s < 8; ++s) {
                const int k0 = (kh * 8 + s) * 32 + quad * 8;
                bf16x8 xF = *reinterpret_cast<const bf16x8*>(&Xhi[l16][k0]);
                p = __builtin_amdgcn_mfma_f32_16x16x32_bf16(aF[s], xF, p, 0, 0, 0);
            }
            if (kh == 1) red4[m][lane] = p;
            __syncthreads();                               // sync#1
            if (kh == 0) {
                f32x4 tot = p + red4[m][lane];
                bf16x4 xh, xl;
#pragma unroll
                for (int j = 0; j < 4; ++j) {
                    float r = fmaxf(tot[j], 0.f);
                    __bf16 hh = (__bf16)r;
                    xh[j] = hh;
                    xl[j] = (__bf16)(r - (float)hh);
                }
                *reinterpret_cast<bf16x4*>(&Xhi[l16][m * 16 + quad * 4])  = xh;
                *reinterpret_cast<bf16x4*>(&Xlo3[l16][m * 16 + quad * 4]) = xl;
            }
        }

        // ---- partial h: D@u (own 32 rows, K-quartered) + C_slice @ X3 ----
        {
            f32x4 hp = {0.f, 0.f, 0.f, 0.f};
#pragma unroll
            for (int s = 0; s < 3; ++s) {
                const int k0 = (kh4 * 3 + s) * 32 + quad * 8;
                bf16x8 uh = *reinterpret_cast<const bf16x8*>(&u_hi[l16][k0]);
                bf16x8 ul = *reinterpret_cast<const bf16x8*>(&u_lo[l16][k0]);
                hp = __builtin_amdgcn_mfma_f32_16x16x32_bf16(dFh[s], uh, hp, 0, 0, 0);
                hp = __builtin_amdgcn_mfma_f32_16x16x32_bf16(dFh[s], ul, hp, 0, 0, 0);
                hp = __builtin_amdgcn_mfma_f32_16x16x32_bf16(dFl[s], uh, hp, 0, 0, 0);
            }
            if (kh4 > 0) red4[4 + m2 * 3 + (kh4 - 1)][lane] = hp;
            __syncthreads();                               // sync#2 (X3 staged too)
            if (kh4 == 0) {
                f32x4 dt = hp + red4[4 + m2 * 3][lane] + red4[4 + m2 * 3 + 1][lane]
                              + red4[4 + m2 * 3 + 2][lane];
#pragma unroll
                for (int j = 0; j < 4; ++j)
                    dsum[m2 * 16 + quad * 4 + j][l16] = dt[j];
            }
            // C-part: wave w -> h-rows [32w,+32), K = own 64 X rows
            f32x4 ph0 = {0.f, 0.f, 0.f, 0.f}, ph1 = {0.f, 0.f, 0.f, 0.f};
#pragma unroll
            for (int s = 0; s < 2; ++s) {
                const int k0 = s * 32 + quad * 8;
                bf16x8 xh = *reinterpret_cast<const bf16x8*>(&Xhi[l16][k0]);
                bf16x8 xl = *reinterpret_cast<const bf16x8*>(&Xlo3[l16][k0]);
                ph0 = __builtin_amdgcn_mfma_f32_16x16x32_bf16(cFh[0][s], xh, ph0, 0, 0, 0);
                ph0 = __builtin_amdgcn_mfma_f32_16x16x32_bf16(cFh[0][s], xl, ph0, 0, 0, 0);
                ph0 = __builtin_amdgcn_mfma_f32_16x16x32_bf16(cFl[0][s], xh, ph0, 0, 0, 0);
                ph1 = __builtin_amdgcn_mfma_f32_16x16x32_bf16(cFh[1][s], xh, ph1, 0, 0, 0);
                ph1 = __builtin_amdgcn_mfma_f32_16x16x32_bf16(cFh[1][s], xl, ph1, 0, 0, 0);
                ph1 = __builtin_amdgcn_mfma_f32_16x16x32_bf16(cFl[1][s], xh, ph1, 0, 0, 0);
            }
            __syncthreads();                               // sync#3 (dsum visible)
            if (wave == sub) {
#pragma unroll
                for (int j = 0; j < 4; ++j) {
                    ph0[j] += dsum[quad * 4 + j][l16];
                    ph1[j] += dsum[16 + quad * 4 + j][l16];
                }
            }
            // store f32 partial: Hpart[g][sub][col l16][row 32*wave + ...]
            u64* hb = reinterpret_cast<u64*>(
                Hpart + (((size_t)g * 8 + sub) * 16 + l16) * 256
                      + 32 * wave + quad * 4);
            st64(hb,     packf2(ph0[0], ph0[1]));
            st64(hb + 1, packf2(ph0[2], ph0[3]));
            st64(hb + 8, packf2(ph1[0], ph1[1]));
            st64(hb + 9, packf2(ph1[2], ph1[3]));
        }
        __syncthreads();  // drain Hpart stores (vmcnt(0) per wave)
        if (tid == 0)
            __hip_atomic_store(fg + 2 * (GW * 16) + sub * 16, tok,
                               __ATOMIC_RELAXED, __HIP_MEMORY_SCOPE_AGENT);
        // waiters poll at the start of timestep t+1
    }

    // ---- tail: h(SEQ-1) -> out[SEQ-1] + h_last ----
    {
        if (wave == 0) group_wait(fg + 2 * (GW * 16), (u32)SEQ, lane, FEN);
        __syncthreads();
        float hv[8];
        read_h_sum(hv);
        if ((xseg >> 2) == sub) {
            float4 o0 = {hv[0], hv[1], hv[2], hv[3]};
            float4 o1 = {hv[4], hv[5], hv[6], hv[7]};
            size_t ob = ((size_t)(b0 + xcol) * SEQ + (SEQ - 1)) * HID + xseg * 8;
            *reinterpret_cast<float4*>(&out[ob])     = o0;
            *reinterpret_cast<float4*>(&out[ob + 4]) = o1;
            size_t hb2 = (size_t)B_SZ * SEQ * HID + (size_t)(b0 + xcol) * HID + xseg * 8;
            *reinterpret_cast<float4*>(&out[hb2])     = o0;
            *reinterpret_cast<float4*>(&out[hb2 + 4]) = o1;
        }
    }
}

extern "C" void kernel_launch(void* const* d_in, const int* in_sizes, int n_in,
                              void* d_out, int out_size, void* d_ws, size_t ws_size,
                              hipStream_t stream) {
    const float* x  = (const float*)d_in[0];
    const float* A  = (const float*)d_in[1];
    const float* Bm = (const float*)d_in[2];
    const float* C  = (const float*)d_in[3];
    const float* D  = (const float*)d_in[4];
    float* out = (float*)d_out;

    char* ws = (char*)d_ws;
    __bf16* Abf = (__bf16*)(ws);               // 524288
    __bf16* Bhi = (__bf16*)(ws + 524288);      // 393216
    __bf16* Blo = (__bf16*)(ws + 917504);
    __bf16* Chi = (__bf16*)(ws + 1310720);     // 262144
    __bf16* Clo = (__bf16*)(ws + 1572864);
    __bf16* Dhi = (__bf16*)(ws + 1835008);     // 196608
    __bf16* Dlo = (__bf16*)(ws + 2031616);
    u32* flags  = (u32*)(ws + 2228224);        // 32*4*8*16*4 = 65536
    u32* Xex    = (u32*)(ws + 2293760);        // 1048576
    float* Hpart= (float*)(ws + 3342336);      // 32*8*16*256*4 = 4194304 -> 7536640

    convert_plain<<<256, 256, 0, stream>>>(A, Abf, 262144 / 4);
    convert_split<<<192, 256, 0, stream>>>(Bm, Bhi, Blo, 196608 / 4);
    convert_split<<<128, 256, 0, stream>>>(C, Chi, Clo, 131072 / 4);
    convert_split<<<96, 256, 0, stream>>>(D, Dhi, Dlo, 98304 / 4);
    zero_u32<<<64, 256, 0, stream>>>(flags, 32 * NEV * GW * 16);

    rnn_kernel<<<256, 512, 0, stream>>>(x, Abf, Bhi, Blo, Chi, Clo, Dhi, Dlo,
                                        out, flags, Xex, Hpart);
}